// Round 5
// baseline (464.451 us; speedup 1.0000x reference)
//
#include <hip/hip_runtime.h>
#include <math.h>

#define NH 16
#define NKV 4
#define HD 128
#define DIM 2048
#define GQ 4   // NH/NKV
#define EPS 1.1920928955078125e-07f

typedef unsigned short u16;
using bf16x8 = __attribute__((ext_vector_type(8))) short;
using f16x4  = __attribute__((ext_vector_type(4))) _Float16;
using f32x4  = __attribute__((ext_vector_type(4))) float;

__device__ inline float fast_exp2(float x) { return __builtin_amdgcn_exp2f(x); }

__device__ inline short f2bf(float f) {
    unsigned u = __builtin_bit_cast(unsigned, f);
    return (short)((u + 0x7FFFu + ((u >> 16) & 1u)) >> 16);
}
__device__ inline u16 f2h(float f) {
    _Float16 h = (_Float16)f;
    return __builtin_bit_cast(u16, h);
}

#define ASYNC_LOAD16(g, l)                                                        \
    __builtin_amdgcn_global_load_lds(                                             \
        (const __attribute__((address_space(1))) unsigned*)(g),                   \
        (__attribute__((address_space(3))) unsigned*)(l), 16, 0, 0)

#define SCHED_FENCE() __builtin_amdgcn_sched_barrier(0)
#define WAIT_LGKM0()  asm volatile("s_waitcnt lgkmcnt(0)" ::: "memory")
#define WAIT_VM(N)    asm volatile("s_waitcnt vmcnt(" #N ")" ::: "memory")

// ------- fused fp32 -> bf16 convert (all 5 tensors) + RoPE tables -----------
__global__ __launch_bounds__(256) void cvt_fused(
    const float* __restrict__ x,  const float* __restrict__ wq,
    const float* __restrict__ wk, const float* __restrict__ wv,
    const float* __restrict__ wp,
    u16* __restrict__ x16, u16* __restrict__ wqkv, u16* __restrict__ wp16,
    float* __restrict__ ct, float* __restrict__ st, float l2b64,
    int nx4, int total, int nblk_cvt) {
    if ((int)blockIdx.x >= nblk_cvt) {
        // RoPE table part: [T][64]
        const int idx = (blockIdx.x - nblk_cvt) * 256 + threadIdx.x;
        const int t = idx >> 6;
        const int j = idx & 63;
        const float inv_freq = fast_exp2(-(float)j * l2b64);
        const float fr = (float)t * inv_freq;
        ct[idx] = cosf(fr);
        st[idx] = sinf(fr);
        return;
    }
    int i = blockIdx.x * 256 + threadIdx.x;
    if (i >= total) return;
    const int nw4 = DIM * DIM / 4;          // 1048576
    const int nk4 = (NKV * HD) * DIM / 4;   // 262144
    const float4* s4;
    ushort4* d4;
    if (i < nx4) {
        s4 = (const float4*)x + i; d4 = (ushort4*)x16 + i;
    } else {
        int j = i - nx4;
        if (j < nw4) {
            s4 = (const float4*)wq + j; d4 = (ushort4*)wqkv + j;
        } else {
            j -= nw4;
            if (j < nk4) {
                s4 = (const float4*)wk + j;
                d4 = (ushort4*)wqkv + (size_t)2048 * DIM / 4 + j;
            } else {
                j -= nk4;
                if (j < nk4) {
                    s4 = (const float4*)wv + j;
                    d4 = (ushort4*)wqkv + (size_t)2560 * DIM / 4 + j;
                } else {
                    j -= nk4;
                    s4 = (const float4*)wp + j; d4 = (ushort4*)wp16 + j;
                }
            }
        }
    }
    float4 f = *s4;
    ushort4 o;
    o.x = (u16)f2bf(f.x); o.y = (u16)f2bf(f.y);
    o.z = (u16)f2bf(f.z); o.w = (u16)f2bf(f.w);
    *d4 = o;
}

// ============ BMx256 4-phase pipelined GEMM, counted vmcnt (T4) =============
#define BN 256
#define BKT 64
#define NKT (DIM / BKT)   // 32

template <int EPI, int MT>
__global__ __launch_bounds__(512, 2) void gemm256(
    const u16* __restrict__ A, const u16* __restrict__ W,
    float* __restrict__ C, int N,                       // EPI==0: plain fp32 C
    u16* __restrict__ q16, u16* __restrict__ k16,       // EPI==1: fused QKV
    u16* __restrict__ vt16,
    const float* __restrict__ ctab, const float* __restrict__ stab,
    const float* __restrict__ q_gain, int T) {
    __shared__ u16 As[2][MT * 64 * BKT];
    __shared__ u16 Bs[2][BN * BKT];

    const int tid  = threadIdx.x;
    const int wid  = tid >> 6;
    const int lane = tid & 63;
    const int l16  = lane & 15;
    const int quad = lane >> 4;
    const int wm   = wid >> 1;          // 0..3  (MT*16 rows each)
    const int wn   = wid & 1;           // 0..1  (128 cols each)
    const int m0   = blockIdx.x * (MT * 64);
    const int n0   = blockIdx.y * BN;
    const int K    = DIM;

    const int srow = lane >> 3;                     // 0..7
    const int scol = ((lane & 7) ^ srow) * 8;       // pre-swizzled source col
    const u16* pa = A + (size_t)(m0 + srow) * K + scol;
    const u16* pw = W + (size_t)(n0 + srow) * K + scol;

    const int ca0 = ((quad)     ^ (l16 & 7)) * 8;   // kk = 0
    const int ca1 = ((4 + quad) ^ (l16 & 7)) * 8;   // kk = 1

    f32x4 acc[MT][8];
#pragma unroll
    for (int i = 0; i < MT; i++)
#pragma unroll
        for (int j = 0; j < 8; j++) acc[i][j] = (f32x4){0.f, 0.f, 0.f, 0.f};

    // ---- prologue: stage tile 0 in steady-state age order ----
#pragma unroll
    for (int r = 0; r < MT; r++)
        ASYNC_LOAD16(pa + (size_t)(r * 64 + wid * 8) * K, &As[0][(r * 64 + wid * 8) * BKT]);
    ASYNC_LOAD16(pw + (size_t)(0 * 64 + wid * 8) * K, &Bs[0][(0 * 64 + wid * 8) * BKT]);
    ASYNC_LOAD16(pw + (size_t)(2 * 64 + wid * 8) * K, &Bs[0][(2 * 64 + wid * 8) * BKT]);
    ASYNC_LOAD16(pw + (size_t)(1 * 64 + wid * 8) * K, &Bs[0][(1 * 64 + wid * 8) * BKT]);
    ASYNC_LOAD16(pw + (size_t)(3 * 64 + wid * 8) * K, &Bs[0][(3 * 64 + wid * 8) * BKT]);
    WAIT_VM(2);                 // a*, b0, b2 landed; b1,b3 may be in flight
    SCHED_FENCE();
    __builtin_amdgcn_s_barrier();
    SCHED_FENCE();

#pragma unroll 1
    for (int kt = 0; kt < NKT; kt++) {
        const int cur = kt & 1;
        const u16* Ac = &As[cur][0];
        const u16* Bc = &Bs[cur][0];
        u16* An = &As[cur ^ 1][0];
        u16* Bn = &Bs[cur ^ 1][0];
        const size_t ko = (size_t)((kt + 1) & (NKT - 1)) * BKT;

        bf16x8 a0[MT], a1[MT];

        // -------- P0: A(kk0) + B(nt0-3,kk0); issue a*(next) ----------------
        {
            bf16x8 bf[4];
#pragma unroll
            for (int mt = 0; mt < MT; mt++)
                a0[mt] = *(const bf16x8*)&Ac[(wm * (MT * 16) + mt * 16 + l16) * BKT + ca0];
#pragma unroll
            for (int nt = 0; nt < 4; nt++)
                bf[nt] = *(const bf16x8*)&Bc[(wn * 128 + nt * 16 + l16) * BKT + ca0];
#pragma unroll
            for (int r = 0; r < MT; r++)
                ASYNC_LOAD16(pa + (size_t)(r * 64 + wid * 8) * K + ko,
                             &An[(r * 64 + wid * 8) * BKT]);
            SCHED_FENCE();
            __builtin_amdgcn_s_barrier();
            WAIT_LGKM0();
            SCHED_FENCE();
            __builtin_amdgcn_s_setprio(1);
#pragma unroll
            for (int mt = 0; mt < MT; mt++)
#pragma unroll
                for (int nt = 0; nt < 4; nt++)
                    acc[mt][nt] = __builtin_amdgcn_mfma_f32_16x16x32_bf16(
                        a0[mt], bf[nt], acc[mt][nt], 0, 0, 0);
            __builtin_amdgcn_s_setprio(0);
            SCHED_FENCE();
            __builtin_amdgcn_s_barrier();
        }

        // -------- P1: A(kk1) + B(nt0-3,kk1); issue b0,b2(next) -------------
        {
            bf16x8 bf[4];
#pragma unroll
            for (int mt = 0; mt < MT; mt++)
                a1[mt] = *(const bf16x8*)&Ac[(wm * (MT * 16) + mt * 16 + l16) * BKT + ca1];
#pragma unroll
            for (int nt = 0; nt < 4; nt++)
                bf[nt] = *(const bf16x8*)&Bc[(wn * 128 + nt * 16 + l16) * BKT + ca1];
            ASYNC_LOAD16(pw + (size_t)(0 * 64 + wid * 8) * K + ko,
                         &Bn[(0 * 64 + wid * 8) * BKT]);
            ASYNC_LOAD16(pw + (size_t)(2 * 64 + wid * 8) * K + ko,
                         &Bn[(2 * 64 + wid * 8) * BKT]);
            SCHED_FENCE();
            __builtin_amdgcn_s_barrier();
            WAIT_LGKM0();
            SCHED_FENCE();
            __builtin_amdgcn_s_setprio(1);
#pragma unroll
            for (int mt = 0; mt < MT; mt++)
#pragma unroll
                for (int nt = 0; nt < 4; nt++)
                    acc[mt][nt] = __builtin_amdgcn_mfma_f32_16x16x32_bf16(
                        a1[mt], bf[nt], acc[mt][nt], 0, 0, 0);
            __builtin_amdgcn_s_setprio(0);
            if constexpr (MT == 4) { WAIT_VM(6); } else { WAIT_VM(4); }
            SCHED_FENCE();
            __builtin_amdgcn_s_barrier();
            SCHED_FENCE();
        }

        // -------- P2: B(nt4-7,kk0), reuse a0; issue b1,b3(next) ------------
        {
            bf16x8 bf[4];
#pragma unroll
            for (int nt = 0; nt < 4; nt++)
                bf[nt] = *(const bf16x8*)&Bc[(wn * 128 + (nt + 4) * 16 + l16) * BKT + ca0];
            ASYNC_LOAD16(pw + (size_t)(1 * 64 + wid * 8) * K + ko,
                         &Bn[(1 * 64 + wid * 8) * BKT]);
            ASYNC_LOAD16(pw + (size_t)(3 * 64 + wid * 8) * K + ko,
                         &Bn[(3 * 64 + wid * 8) * BKT]);
            SCHED_FENCE();
            __builtin_amdgcn_s_barrier();
            WAIT_LGKM0();
            SCHED_FENCE();
            __builtin_amdgcn_s_setprio(1);
#pragma unroll
            for (int mt = 0; mt < MT; mt++)
#pragma unroll
                for (int nt = 0; nt < 4; nt++)
                    acc[mt][nt + 4] = __builtin_amdgcn_mfma_f32_16x16x32_bf16(
                        a0[mt], bf[nt], acc[mt][nt + 4], 0, 0, 0);
            __builtin_amdgcn_s_setprio(0);
            SCHED_FENCE();
            __builtin_amdgcn_s_barrier();
        }

        // -------- P3: B(nt4-7,kk1), reuse a1; no issue ---------------------
        {
            bf16x8 bf[4];
#pragma unroll
            for (int nt = 0; nt < 4; nt++)
                bf[nt] = *(const bf16x8*)&Bc[(wn * 128 + (nt + 4) * 16 + l16) * BKT + ca1];
            SCHED_FENCE();
            __builtin_amdgcn_s_barrier();
            WAIT_LGKM0();
            SCHED_FENCE();
            __builtin_amdgcn_s_setprio(1);
#pragma unroll
            for (int mt = 0; mt < MT; mt++)
#pragma unroll
                for (int nt = 0; nt < 4; nt++)
                    acc[mt][nt + 4] = __builtin_amdgcn_mfma_f32_16x16x32_bf16(
                        a1[mt], bf[nt], acc[mt][nt + 4], 0, 0, 0);
            __builtin_amdgcn_s_setprio(0);
            WAIT_VM(2);   // retire a*,b0,b2 of NEXT tile; b1,b3 stay in flight
            SCHED_FENCE();
            __builtin_amdgcn_s_barrier();
            SCHED_FENCE();
        }
    }
    WAIT_VM(0);   // drain wrap-around dummy loads before epilogue/endpgm

    // --------------------------- epilogues ---------------------------------
    if constexpr (EPI == 0) {
#pragma unroll
        for (int mt = 0; mt < MT; mt++)
#pragma unroll
            for (int nt = 0; nt < 8; nt++)
#pragma unroll
                for (int r = 0; r < 4; r++)
                    C[(size_t)(m0 + wm * (MT * 16) + mt * 16 + quad * 4 + r) * N +
                      n0 + wn * 128 + nt * 16 + l16] = acc[mt][nt][r];
    } else {
        const int nb = n0 + wn * 128;           // head-aligned column base
        if (nb < 2560) {                        // ---- Q or K: RMSNorm + RoPE
            const bool isQ = (nb < 2048);
            const float gval =
                isQ ? (q_gain[nb >> 7] * 0.08838834764831843f * 1.4426950408889634f)
                    : 1.0f;
#pragma unroll
            for (int mt = 0; mt < MT; mt++) {
#pragma unroll
                for (int r = 0; r < 4; r++) {
                    float s = 0.f;
#pragma unroll
                    for (int nt = 0; nt < 8; nt++) {
                        float a = acc[mt][nt][r];
                        s = fmaf(a, a, s);
                    }
                    s += __shfl_xor(s, 1);
                    s += __shfl_xor(s, 2);
                    s += __shfl_xor(s, 4);
                    s += __shfl_xor(s, 8);
                    const float scale = rsqrtf(s * (1.0f / HD) + EPS) * gval;
                    const int m = m0 + wm * (MT * 16) + mt * 16 + quad * 4 + r;
                    const int t = m & (T - 1);
                    const float* ct = ctab + t * 64;
                    const float* st = stab + t * 64;
                    u16* dst = isQ ? (q16 + (size_t)m * 2048 + nb)
                                   : (k16 + (size_t)m * 512 + (nb - 2048));
#pragma unroll
                    for (int nt = 0; nt < 4; nt++) {
                        const int j = nt * 16 + l16;
                        const float c = ct[j], sn = st[j];
                        const float x1 = acc[mt][nt][r] * scale;
                        const float x2 = acc[mt][nt + 4][r] * scale;
                        dst[j]      = (u16)f2bf(x1 * c + x2 * sn);
                        dst[j + 64] = (u16)f2bf(x2 * c - x1 * sn);
                    }
                }
            }
        } else {                                // ---- V: f16, transposed [d][t]
#pragma unroll
            for (int mt = 0; mt < MT; mt++) {
                const int mb = m0 + wm * (MT * 16) + mt * 16 + quad * 4;
                const int b = mb >> 11;          // T == 2048
                const int t0 = mb & (T - 1);
#pragma unroll
                for (int nt = 0; nt < 8; nt++) {
                    const int dcol = nb - 2560 + nt * 16 + l16;
                    const int kvh = dcol >> 7;
                    const int d = dcol & (HD - 1);
                    ushort4 o;
                    o.x = f2h(acc[mt][nt][0]);
                    o.y = f2h(acc[mt][nt][1]);
                    o.z = f2h(acc[mt][nt][2]);
                    o.w = f2h(acc[mt][nt][3]);
                    *(ushort4*)(vt16 + ((size_t)((b * NKV + kvh) * HD + d)) * T + t0) = o;
                }
            }
        }
    }
}

// ------ flash attention v7: spill-free 2-stage pipeline (T15) + setprio -----
// Per iter it: QK^T(it) -> stage (it&1)  [MFMA cluster, issues early]
//              finish(tile it-1) from stage ((it-1)&1)  [VALU + PV MFMA]
// The two S-tile stages are 8 individually-named f32x4 regs; all code is
// macro-expanded with compile-time indices -- NO lambdas, NO array refs,
// NO runtime-indexed register arrays (round-4 spill post-mortem).
// V triple-buffered (PV consumes V one iter late); K double-buffered.
// LDS: K 2x16KB + V 3x16KB = 80KB -> 2 blocks/CU = 16 waves/CU.
#define QT 128
#define SK 64

// QK^T for one K-tile: D0..D3 = S^T quadrants (rows st*16+l16)
#define QKT(D0, D1, D2, D3, KB)                                               \
    do {                                                                      \
        D0 = (f32x4){0.f, 0.f, 0.f, 0.f}; D1 = D0; D2 = D0; D3 = D0;          \
        __builtin_amdgcn_s_setprio(1);                                        \
        _Pragma("unroll")                                                     \
        for (int kc = 0; kc < 4; kc++) {                                      \
            const int co = ((kc * 4 + quad) ^ l16) * 8;                       \
            bf16x8 kf;                                                        \
            kf = *(const bf16x8*)&(KB)[(0 * 16 + l16) * 128 + co];            \
            D0 = __builtin_amdgcn_mfma_f32_16x16x32_bf16(kf, qf[kc], D0, 0, 0, 0); \
            kf = *(const bf16x8*)&(KB)[(1 * 16 + l16) * 128 + co];            \
            D1 = __builtin_amdgcn_mfma_f32_16x16x32_bf16(kf, qf[kc], D1, 0, 0, 0); \
            kf = *(const bf16x8*)&(KB)[(2 * 16 + l16) * 128 + co];            \
            D2 = __builtin_amdgcn_mfma_f32_16x16x32_bf16(kf, qf[kc], D2, 0, 0, 0); \
            kf = *(const bf16x8*)&(KB)[(3 * 16 + l16) * 128 + co];            \
            D3 = __builtin_amdgcn_mfma_f32_16x16x32_bf16(kf, qf[kc], D3, 0, 0, 0); \
        }                                                                     \
        __builtin_amdgcn_s_setprio(0);                                        \
    } while (0)

#define MASKD(D0, D1, D2, D3, S0OFF)                                          \
    do {                                                                      \
        _Pragma("unroll")                                                     \
        for (int r = 0; r < 4; r++) {                                         \
            if ((S0OFF) + 0 * 16 + quad * 4 + r > qglob) D0[r] = -1e30f;      \
            if ((S0OFF) + 1 * 16 + quad * 4 + r > qglob) D1[r] = -1e30f;      \
            if ((S0OFF) + 2 * 16 + quad * 4 + r > qglob) D2[r] = -1e30f;      \
            if ((S0OFF) + 3 * 16 + quad * 4 + r > qglob) D3[r] = -1e30f;      \
        }                                                                     \
    } while (0)

#define PVST(PF, ST, VB)                                                      \
    do {                                                                      \
        const int clog = (ST) * 2 + (quad >> 1);                              \
        const int phys = clog ^ (l16 & 7);                                    \
        _Pragma("unroll")                                                     \
        for (int dt = 0; dt < 8; dt++) {                                      \
            const int d = dt * 16 + l16;                                      \
            f16x4 va = *(const f16x4*)&(VB)[d * 64 + phys * 8 + (quad & 1) * 4]; \
            of[dt] = __builtin_amdgcn_mfma_f32_16x16x16f16(va, PF, of[dt], 0, 0, 0); \
        }                                                                     \
    } while (0)

// softmax + PV for one finished tile held in S0..S3, V in VB
#define FINISH(S0, S1, S2, S3, VB)                                            \
    do {                                                                      \
        float tm = fmaxf(fmaxf(S0[0], S0[1]), fmaxf(S0[2], S0[3]));           \
        tm = fmaxf(tm, fmaxf(fmaxf(S1[0], S1[1]), fmaxf(S1[2], S1[3])));      \
        tm = fmaxf(tm, fmaxf(fmaxf(S2[0], S2[1]), fmaxf(S2[2], S2[3])));      \
        tm = fmaxf(tm, fmaxf(fmaxf(S3[0], S3[1]), fmaxf(S3[2], S3[3])));      \
        tm = fmaxf(tm, __shfl_xor(tm, 16));                                   \
        tm = fmaxf(tm, __shfl_xor(tm, 32));                                   \
        if (__ballot(tm > m_i + 8.0f)) {  /* defer-max (T13) */               \
            const float mnew = fmaxf(m_i, tm);                                \
            const float alpha = fast_exp2(m_i - mnew);                        \
            m_i = mnew; l_i *= alpha;                                         \
            _Pragma("unroll")                                                 \
            for (int dt = 0; dt < 8; dt++)                                    \
                _Pragma("unroll")                                             \
                for (int r = 0; r < 4; r++) of[dt][r] *= alpha;               \
        }                                                                     \
        f16x4 pf0, pf1, pf2, pf3;                                             \
        float ls = 0.0f;                                                      \
        _Pragma("unroll")                                                     \
        for (int r = 0; r < 4; r++) {                                         \
            float e0 = fast_exp2(S0[r] - m_i); ls += e0; pf0[r] = (_Float16)e0; \
            float e1 = fast_exp2(S1[r] - m_i); ls += e1; pf1[r] = (_Float16)e1; \
            float e2 = fast_exp2(S2[r] - m_i); ls += e2; pf2[r] = (_Float16)e2; \
            float e3 = fast_exp2(S3[r] - m_i); ls += e3; pf3[r] = (_Float16)e3; \
        }                                                                     \
        ls += __shfl_xor(ls, 16);                                             \
        ls += __shfl_xor(ls, 32);                                             \
        l_i += ls;                                                            \
        __builtin_amdgcn_s_setprio(1);                                        \
        PVST(pf0, 0, VB); PVST(pf1, 1, VB);                                   \
        PVST(pf2, 2, VB); PVST(pf3, 3, VB);                                   \
        __builtin_amdgcn_s_setprio(0);                                        \
    } while (0)

__global__ __launch_bounds__(512, 4) void flash7(const u16* __restrict__ q16,
                                                 const u16* __restrict__ k16,
                                                 const u16* __restrict__ vt16,
                                                 u16* __restrict__ y16, int T) {
    __shared__ u16 Ks[2][SK * 128];
    __shared__ u16 Vt[3][HD * 64];

    const int tid = threadIdx.x;
    const int wave = tid >> 6;        // 0..7
    const int lane = tid & 63;
    const int l16 = lane & 15;
    const int quad = lane >> 4;

    const int bid = blockIdx.x;
    const int bh = bid & 31;          // b*NH + h
    const int qi = bid >> 5;          // 0..nqt-1
    const int nqt = T / QT;           // 16
    const int qt = (qi < (nqt >> 1)) ? qi : (nqt - 1 - (qi - (nqt >> 1)));
    const int h = bh & 15;
    const int b = bh >> 4;
    const int kv = h / GQ;

    const u16* kg = k16 + ((size_t)b * T * NKV + kv) * HD;
    const u16* vg = vt16 + (size_t)(b * NKV + kv) * HD * T;

    const int krow_in_seg = lane >> 4;          // 0..3
    const int kclog_base = lane & 15;           // phys chunk; logical = phys ^ (r&15)
    const int vrow_in_seg = lane >> 3;          // 0..7
    const int vclog = (lane & 7) ^ (lane >> 3); // logical chunk

    const int q0 = qt * QT;
    const int qglob = q0 + wave * 16 + l16;
    const int nts = q0 / SK + 2;      // two diagonal tiles

    bf16x8 qf[4];
    {
        const u16* qp = q16 + ((size_t)(b * T + qglob) * NH + h) * HD;
#pragma unroll
        for (int kc = 0; kc < 4; kc++)
            qf[kc] = *(const bf16x8*)(qp + kc * 32 + quad * 8);
    }

    f32x4 of[8];
#pragma unroll
    for (int i = 0; i < 8; i++) of[i] = (f32x4){0.f, 0.f, 0.f, 0.f};
    float m_i = -1e30f, l_i = 0.0f;

    // preload tile 0: 16 K segs + 16 V segs, 2+2 per wave
#pragma unroll
    for (int j = 0; j < 2; j++) {
        const int seg = wave * 2 + j;
        const int r = seg * 4 + krow_in_seg;
        const int clog = kclog_base ^ (r & 15);
        ASYNC_LOAD16(kg + (size_t)r * (NKV * HD) + clog * 8, &Ks[0][seg * 512]);
        const int d = seg * 8 + vrow_in_seg;
        ASYNC_LOAD16(vg + (size_t)d * T + vclog * 8, &Vt[0][seg * 512]);
    }

    // the two pipeline stages: 8 individually-named f32x4 (no arrays!)
    f32x4 sA0, sA1, sA2, sA3, sB0, sB1, sB2, sB3;

#pragma unroll 1
    for (int it = 0; it < nts; ++it) {
        __syncthreads();   // drains DMA for tile `it` (one full phase flight)

        if (it + 1 < nts) {
            const int s1 = (it + 1) * SK;
            u16* kn = &Ks[(it + 1) & 1][0];
            u16* vn = &Vt[0][0] + ((it + 1) % 3) * (HD * 64);
#pragma unroll
            for (int j = 0; j < 2; j++) {
                const int seg = wave * 2 + j;
                const int r = seg * 4 + krow_in_seg;
                const int clog = kclog_base ^ (r & 15);
                ASYNC_LOAD16(kg + (size_t)(s1 + r) * (NKV * HD) + clog * 8,
                             kn + seg * 512);
                const int d = seg * 8 + vrow_in_seg;
                ASYNC_LOAD16(vg + (size_t)d * T + s1 + vclog * 8,
                             vn + seg * 512);
            }
        }

        // QK^T(it) into stage (it&1); light waves skip fully-masked last tile
        const bool skipQK = (it == nts - 1 && wave < 4);
        const u16* Kc = &Ks[it & 1][0];
        if (it & 1) {
            if (!skipQK) QKT(sB0, sB1, sB2, sB3, Kc);
        } else {
            if (!skipQK) QKT(sA0, sA1, sA2, sA3, Kc);
        }

        // finish tile it-1 (overlaps the QK^T MFMAs above)
        if (it > 0) {
            const int fin = it - 1;
            const u16* vbp = &Vt[0][0] + (fin % 3) * (HD * 64);
            if (it & 1) {   // fin even -> stage A
                if (fin >= nts - 2) MASKD(sA0, sA1, sA2, sA3, fin * SK);
                FINISH(sA0, sA1, sA2, sA3, vbp);
            } else {        // fin odd -> stage B
                if (fin >= nts - 2) MASKD(sB0, sB1, sB2, sB3, fin * SK);
                FINISH(sB0, sB1, sB2, sB3, vbp);
            }
        }
    }
    // pipeline tail: tile nts-1 (heavy waves only; light waves skipped its QK)
    if (wave >= 4) {
        const int fin = nts - 1;
        const u16* vbp = &Vt[0][0] + (fin % 3) * (HD * 64);
        if (fin & 1) {
            MASKD(sB0, sB1, sB2, sB3, fin * SK);
            FINISH(sB0, sB1, sB2, sB3, vbp);
        } else {
            MASKD(sA0, sA1, sA2, sA3, fin * SK);
            FINISH(sA0, sA1, sA2, sA3, vbp);
        }
    }

    const float inv = 1.0f / l_i;
    u16* yp = y16 + ((size_t)(b * T + qglob) * NH + h) * HD + quad * 4;
#pragma unroll
    for (int dt = 0; dt < 8; dt++) {
        ushort4 o;
        o.x = (u16)f2bf(of[dt][0] * inv);
        o.y = (u16)f2bf(of[dt][1] * inv);
        o.z = (u16)f2bf(of[dt][2] * inv);
        o.w = (u16)f2bf(of[dt][3] * inv);
        *(ushort4*)(yp + dt * 16) = o;
    }
}

// ---------------------------------------------------------------------------
extern "C" void kernel_launch(void* const* d_in, const int* in_sizes, int n_in,
                              void* d_out, int out_size, void* d_ws, size_t ws_size,
                              hipStream_t stream) {
    const float* x      = (const float*)d_in[0];
    const float* Wq     = (const float*)d_in[1];
    const float* Wk     = (const float*)d_in[2];
    const float* Wv     = (const float*)d_in[3];
    const float* Wp     = (const float*)d_in[4];
    const float* q_gain = (const float*)d_in[5];
    float* out = (float*)d_out;

    const int B = 2;
    const int BT = in_sizes[0] / DIM;      // 4096
    const int T = BT / B;                  // 2048
    const int KD = NKV * HD;               // 512

    u16* x16   = (u16*)d_ws;                        // BT*DIM        (later y16)
    u16* wqkv  = x16 + (size_t)BT * DIM;            // 3072*DIM
    u16* wp16  = wqkv + (size_t)3072 * DIM;         // DIM*DIM
    u16* q16   = wp16 + (size_t)DIM * DIM;          // BT*DIM
    u16* k16   = q16 + (size_t)BT * DIM;            // BT*KD
    u16* vt16  = k16 + (size_t)BT * KD;             // BT*KD
    float* ctab = (float*)(vt16 + (size_t)BT * KD); // T*64
    float* stab = ctab + (size_t)T * 64;            // T*64
    u16* y16   = x16;

    double base = 10000.0;
    if (T > 1024) base = 10000.0 * pow((double)T / 1024.0, 128.0 / 126.0);
    const float l2b64 = (float)(log2(base) / 64.0);

    const int nx4  = BT * DIM / 4;
    const int total4 = nx4 + 2 * (DIM * DIM / 4) + 2 * (KD * DIM / 4);
    const int nblk_cvt = (total4 + 255) / 256;
    const int nblk_rope = (T * 64 + 255) / 256;

    cvt_fused<<<nblk_cvt + nblk_rope, 256, 0, stream>>>(
        x, Wq, Wk, Wv, Wp, x16, wqkv, wp16, ctab, stab, l2b64, nx4, total4, nblk_cvt);

    gemm256<1, 4><<<dim3(BT / 256, 3072 / BN), 512, 0, stream>>>(
        x16, wqkv, nullptr, 0, q16, k16, vt16, ctab, stab, q_gain, T);

    flash7<<<32 * (T / QT), 512, 0, stream>>>(q16, k16, vt16, y16, T);

    gemm256<0, 2><<<dim3(BT / 128, DIM / BN), 512, 0, stream>>>(
        y16, wp16, out, DIM, nullptr, nullptr, nullptr, nullptr, nullptr, nullptr, T);
}

// Round 6
// 303.144 us; speedup vs baseline: 1.5321x; 1.5321x over previous
//
#include <hip/hip_runtime.h>
#include <math.h>

#define NH 16
#define NKV 4
#define HD 128
#define DIM 2048
#define GQ 4   // NH/NKV
#define EPS 1.1920928955078125e-07f

typedef unsigned short u16;
using bf16x8 = __attribute__((ext_vector_type(8))) short;
using f16x4  = __attribute__((ext_vector_type(4))) _Float16;
using f32x4  = __attribute__((ext_vector_type(4))) float;

__device__ inline float fast_exp2(float x) { return __builtin_amdgcn_exp2f(x); }

__device__ inline short f2bf(float f) {
    unsigned u = __builtin_bit_cast(unsigned, f);
    return (short)((u + 0x7FFFu + ((u >> 16) & 1u)) >> 16);
}
__device__ inline u16 f2h(float f) {
    _Float16 h = (_Float16)f;
    return __builtin_bit_cast(u16, h);
}

#define ASYNC_LOAD16(g, l)                                                        \
    __builtin_amdgcn_global_load_lds(                                             \
        (const __attribute__((address_space(1))) unsigned*)(g),                   \
        (__attribute__((address_space(3))) unsigned*)(l), 16, 0, 0)

#define SCHED_FENCE() __builtin_amdgcn_sched_barrier(0)
#define WAIT_LGKM0()  asm volatile("s_waitcnt lgkmcnt(0)" ::: "memory")
#define WAIT_VM(N)    asm volatile("s_waitcnt vmcnt(" #N ")" ::: "memory")

// ------- fused fp32 -> bf16 convert (all 5 tensors) + RoPE tables -----------
__global__ __launch_bounds__(256) void cvt_fused(
    const float* __restrict__ x,  const float* __restrict__ wq,
    const float* __restrict__ wk, const float* __restrict__ wv,
    const float* __restrict__ wp,
    u16* __restrict__ x16, u16* __restrict__ wqkv, u16* __restrict__ wp16,
    float* __restrict__ ct, float* __restrict__ st, float l2b64,
    int nx4, int total, int nblk_cvt) {
    if ((int)blockIdx.x >= nblk_cvt) {
        // RoPE table part: [T][64]
        const int idx = (blockIdx.x - nblk_cvt) * 256 + threadIdx.x;
        const int t = idx >> 6;
        const int j = idx & 63;
        const float inv_freq = fast_exp2(-(float)j * l2b64);
        const float fr = (float)t * inv_freq;
        ct[idx] = cosf(fr);
        st[idx] = sinf(fr);
        return;
    }
    int i = blockIdx.x * 256 + threadIdx.x;
    if (i >= total) return;
    const int nw4 = DIM * DIM / 4;          // 1048576
    const int nk4 = (NKV * HD) * DIM / 4;   // 262144
    const float4* s4;
    ushort4* d4;
    if (i < nx4) {
        s4 = (const float4*)x + i; d4 = (ushort4*)x16 + i;
    } else {
        int j = i - nx4;
        if (j < nw4) {
            s4 = (const float4*)wq + j; d4 = (ushort4*)wqkv + j;
        } else {
            j -= nw4;
            if (j < nk4) {
                s4 = (const float4*)wk + j;
                d4 = (ushort4*)wqkv + (size_t)2048 * DIM / 4 + j;
            } else {
                j -= nk4;
                if (j < nk4) {
                    s4 = (const float4*)wv + j;
                    d4 = (ushort4*)wqkv + (size_t)2560 * DIM / 4 + j;
                } else {
                    j -= nk4;
                    s4 = (const float4*)wp + j; d4 = (ushort4*)wp16 + j;
                }
            }
        }
    }
    float4 f = *s4;
    ushort4 o;
    o.x = (u16)f2bf(f.x); o.y = (u16)f2bf(f.y);
    o.z = (u16)f2bf(f.z); o.w = (u16)f2bf(f.w);
    *d4 = o;
}

// ============ BMx256 4-phase pipelined GEMM, counted vmcnt (T4) =============
// Barriers only where a buffer handoff requires them (P1-end, P3-end) plus
// the leading alignment barrier of each phase.  P0/P2 trailing barriers
// removed (hazard inventory: no LDS handoff there; see round-6 notes).
#define BN 256
#define BKT 64
#define NKT (DIM / BKT)   // 32

template <int EPI, int MT>
__global__ __launch_bounds__(512, 2) void gemm256(
    const u16* __restrict__ A, const u16* __restrict__ W,
    float* __restrict__ C, int N,                       // EPI==0: plain fp32 C
    u16* __restrict__ q16, u16* __restrict__ k16,       // EPI==1: fused QKV
    u16* __restrict__ vt16,
    const float* __restrict__ ctab, const float* __restrict__ stab,
    const float* __restrict__ q_gain, int T) {
    __shared__ u16 As[2][MT * 64 * BKT];
    __shared__ u16 Bs[2][BN * BKT];

    const int tid  = threadIdx.x;
    const int wid  = tid >> 6;
    const int lane = tid & 63;
    const int l16  = lane & 15;
    const int quad = lane >> 4;
    const int wm   = wid >> 1;          // 0..3  (MT*16 rows each)
    const int wn   = wid & 1;           // 0..1  (128 cols each)
    const int m0   = blockIdx.x * (MT * 64);
    const int n0   = blockIdx.y * BN;
    const int K    = DIM;

    const int srow = lane >> 3;                     // 0..7
    const int scol = ((lane & 7) ^ srow) * 8;       // pre-swizzled source col
    const u16* pa = A + (size_t)(m0 + srow) * K + scol;
    const u16* pw = W + (size_t)(n0 + srow) * K + scol;

    const int ca0 = ((quad)     ^ (l16 & 7)) * 8;   // kk = 0
    const int ca1 = ((4 + quad) ^ (l16 & 7)) * 8;   // kk = 1

    f32x4 acc[MT][8];
#pragma unroll
    for (int i = 0; i < MT; i++)
#pragma unroll
        for (int j = 0; j < 8; j++) acc[i][j] = (f32x4){0.f, 0.f, 0.f, 0.f};

    // ---- prologue: stage tile 0 in steady-state age order ----
#pragma unroll
    for (int r = 0; r < MT; r++)
        ASYNC_LOAD16(pa + (size_t)(r * 64 + wid * 8) * K, &As[0][(r * 64 + wid * 8) * BKT]);
    ASYNC_LOAD16(pw + (size_t)(0 * 64 + wid * 8) * K, &Bs[0][(0 * 64 + wid * 8) * BKT]);
    ASYNC_LOAD16(pw + (size_t)(2 * 64 + wid * 8) * K, &Bs[0][(2 * 64 + wid * 8) * BKT]);
    ASYNC_LOAD16(pw + (size_t)(1 * 64 + wid * 8) * K, &Bs[0][(1 * 64 + wid * 8) * BKT]);
    ASYNC_LOAD16(pw + (size_t)(3 * 64 + wid * 8) * K, &Bs[0][(3 * 64 + wid * 8) * BKT]);
    WAIT_VM(2);                 // a*, b0, b2 landed; b1,b3 may be in flight
    SCHED_FENCE();
    __builtin_amdgcn_s_barrier();
    SCHED_FENCE();

#pragma unroll 1
    for (int kt = 0; kt < NKT; kt++) {
        const int cur = kt & 1;
        const u16* Ac = &As[cur][0];
        const u16* Bc = &Bs[cur][0];
        u16* An = &As[cur ^ 1][0];
        u16* Bn = &Bs[cur ^ 1][0];
        const size_t ko = (size_t)((kt + 1) & (NKT - 1)) * BKT;

        bf16x8 a0[MT], a1[MT];

        // -------- P0: A(kk0) + B(nt0-3,kk0); issue a*(next) ----------------
        {
            bf16x8 bf[4];
#pragma unroll
            for (int mt = 0; mt < MT; mt++)
                a0[mt] = *(const bf16x8*)&Ac[(wm * (MT * 16) + mt * 16 + l16) * BKT + ca0];
#pragma unroll
            for (int nt = 0; nt < 4; nt++)
                bf[nt] = *(const bf16x8*)&Bc[(wn * 128 + nt * 16 + l16) * BKT + ca0];
#pragma unroll
            for (int r = 0; r < MT; r++)
                ASYNC_LOAD16(pa + (size_t)(r * 64 + wid * 8) * K + ko,
                             &An[(r * 64 + wid * 8) * BKT]);
            SCHED_FENCE();
            __builtin_amdgcn_s_barrier();
            WAIT_LGKM0();
            SCHED_FENCE();
            __builtin_amdgcn_s_setprio(1);
#pragma unroll
            for (int mt = 0; mt < MT; mt++)
#pragma unroll
                for (int nt = 0; nt < 4; nt++)
                    acc[mt][nt] = __builtin_amdgcn_mfma_f32_16x16x32_bf16(
                        a0[mt], bf[nt], acc[mt][nt], 0, 0, 0);
            __builtin_amdgcn_s_setprio(0);
            // no trailing barrier: no LDS handoff between P0-MFMA and P1
        }

        // -------- P1: A(kk1) + B(nt0-3,kk1); issue b0,b2(next) -------------
        {
            bf16x8 bf[4];
#pragma unroll
            for (int mt = 0; mt < MT; mt++)
                a1[mt] = *(const bf16x8*)&Ac[(wm * (MT * 16) + mt * 16 + l16) * BKT + ca1];
#pragma unroll
            for (int nt = 0; nt < 4; nt++)
                bf[nt] = *(const bf16x8*)&Bc[(wn * 128 + nt * 16 + l16) * BKT + ca1];
            ASYNC_LOAD16(pw + (size_t)(0 * 64 + wid * 8) * K + ko,
                         &Bn[(0 * 64 + wid * 8) * BKT]);
            ASYNC_LOAD16(pw + (size_t)(2 * 64 + wid * 8) * K + ko,
                         &Bn[(2 * 64 + wid * 8) * BKT]);
            SCHED_FENCE();
            __builtin_amdgcn_s_barrier();
            WAIT_LGKM0();
            SCHED_FENCE();
            __builtin_amdgcn_s_setprio(1);
#pragma unroll
            for (int mt = 0; mt < MT; mt++)
#pragma unroll
                for (int nt = 0; nt < 4; nt++)
                    acc[mt][nt] = __builtin_amdgcn_mfma_f32_16x16x32_bf16(
                        a1[mt], bf[nt], acc[mt][nt], 0, 0, 0);
            __builtin_amdgcn_s_setprio(0);
            if constexpr (MT == 4) { WAIT_VM(6); } else { WAIT_VM(4); }
            SCHED_FENCE();
            __builtin_amdgcn_s_barrier();   // handoff: b1,b3 of CURRENT tile
            SCHED_FENCE();
        }

        // -------- P2: B(nt4-7,kk0), reuse a0; issue b1,b3(next) ------------
        {
            bf16x8 bf[4];
#pragma unroll
            for (int nt = 0; nt < 4; nt++)
                bf[nt] = *(const bf16x8*)&Bc[(wn * 128 + (nt + 4) * 16 + l16) * BKT + ca0];
            ASYNC_LOAD16(pw + (size_t)(1 * 64 + wid * 8) * K + ko,
                         &Bn[(1 * 64 + wid * 8) * BKT]);
            ASYNC_LOAD16(pw + (size_t)(3 * 64 + wid * 8) * K + ko,
                         &Bn[(3 * 64 + wid * 8) * BKT]);
            SCHED_FENCE();
            __builtin_amdgcn_s_barrier();
            WAIT_LGKM0();
            SCHED_FENCE();
            __builtin_amdgcn_s_setprio(1);
#pragma unroll
            for (int mt = 0; mt < MT; mt++)
#pragma unroll
                for (int nt = 0; nt < 4; nt++)
                    acc[mt][nt + 4] = __builtin_amdgcn_mfma_f32_16x16x32_bf16(
                        a0[mt], bf[nt], acc[mt][nt + 4], 0, 0, 0);
            __builtin_amdgcn_s_setprio(0);
            // no trailing barrier: no LDS handoff between P2-MFMA and P3
        }

        // -------- P3: B(nt4-7,kk1), reuse a1; no issue ---------------------
        {
            bf16x8 bf[4];
#pragma unroll
            for (int nt = 0; nt < 4; nt++)
                bf[nt] = *(const bf16x8*)&Bc[(wn * 128 + (nt + 4) * 16 + l16) * BKT + ca1];
            SCHED_FENCE();
            __builtin_amdgcn_s_barrier();
            WAIT_LGKM0();
            SCHED_FENCE();
            __builtin_amdgcn_s_setprio(1);
#pragma unroll
            for (int mt = 0; mt < MT; mt++)
#pragma unroll
                for (int nt = 0; nt < 4; nt++)
                    acc[mt][nt + 4] = __builtin_amdgcn_mfma_f32_16x16x32_bf16(
                        a1[mt], bf[nt], acc[mt][nt + 4], 0, 0, 0);
            __builtin_amdgcn_s_setprio(0);
            WAIT_VM(2);   // retire a*,b0,b2 of NEXT tile; b1,b3 stay in flight
            SCHED_FENCE();
            __builtin_amdgcn_s_barrier();   // handoff: next tile's a*,b0,b2
            SCHED_FENCE();
        }
    }
    WAIT_VM(0);   // drain wrap-around dummy loads before epilogue/endpgm

    // --------------------------- epilogues ---------------------------------
    if constexpr (EPI == 0) {
#pragma unroll
        for (int mt = 0; mt < MT; mt++)
#pragma unroll
            for (int nt = 0; nt < 8; nt++)
#pragma unroll
                for (int r = 0; r < 4; r++)
                    C[(size_t)(m0 + wm * (MT * 16) + mt * 16 + quad * 4 + r) * N +
                      n0 + wn * 128 + nt * 16 + l16] = acc[mt][nt][r];
    } else {
        const int nb = n0 + wn * 128;           // head-aligned column base
        if (nb < 2560) {                        // ---- Q or K: RMSNorm + RoPE
            const bool isQ = (nb < 2048);
            const float gval =
                isQ ? (q_gain[nb >> 7] * 0.08838834764831843f * 1.4426950408889634f)
                    : 1.0f;
#pragma unroll
            for (int mt = 0; mt < MT; mt++) {
#pragma unroll
                for (int r = 0; r < 4; r++) {
                    float s = 0.f;
#pragma unroll
                    for (int nt = 0; nt < 8; nt++) {
                        float a = acc[mt][nt][r];
                        s = fmaf(a, a, s);
                    }
                    s += __shfl_xor(s, 1);
                    s += __shfl_xor(s, 2);
                    s += __shfl_xor(s, 4);
                    s += __shfl_xor(s, 8);
                    const float scale = rsqrtf(s * (1.0f / HD) + EPS) * gval;
                    const int m = m0 + wm * (MT * 16) + mt * 16 + quad * 4 + r;
                    const int t = m & (T - 1);
                    const float* ct = ctab + t * 64;
                    const float* st = stab + t * 64;
                    u16* dst = isQ ? (q16 + (size_t)m * 2048 + nb)
                                   : (k16 + (size_t)m * 512 + (nb - 2048));
#pragma unroll
                    for (int nt = 0; nt < 4; nt++) {
                        const int j = nt * 16 + l16;
                        const float c = ct[j], sn = st[j];
                        const float x1 = acc[mt][nt][r] * scale;
                        const float x2 = acc[mt][nt + 4][r] * scale;
                        dst[j]      = (u16)f2bf(x1 * c + x2 * sn);
                        dst[j + 64] = (u16)f2bf(x2 * c - x1 * sn);
                    }
                }
            }
        } else {                                // ---- V: f16, transposed [d][t]
#pragma unroll
            for (int mt = 0; mt < MT; mt++) {
                const int mb = m0 + wm * (MT * 16) + mt * 16 + quad * 4;
                const int b = mb >> 11;          // T == 2048
                const int t0 = mb & (T - 1);
#pragma unroll
                for (int nt = 0; nt < 8; nt++) {
                    const int dcol = nb - 2560 + nt * 16 + l16;
                    const int kvh = dcol >> 7;
                    const int d = dcol & (HD - 1);
                    ushort4 o;
                    o.x = f2h(acc[mt][nt][0]);
                    o.y = f2h(acc[mt][nt][1]);
                    o.z = f2h(acc[mt][nt][2]);
                    o.w = f2h(acc[mt][nt][3]);
                    *(ushort4*)(vt16 + ((size_t)((b * NKV + kvh) * HD + d)) * T + t0) = o;
                }
            }
        }
    }
}

// ------ flash attention v5 (proven 75.5 us): 8 waves, QT=128 ----------------
// S^T = K Q^T (bf16 x32); softmax in registers (exp2, defer-max THR=8);
// O^T = V^T P^T (f16 x16).  XOR-swizzled K/V LDS, DMA double buffer.
// Grid: 32 bh x 16 qt.  qt mapping: block i and i+256 land on the same CU
// (round-robin) and get qt and 15-qt -> constant work per CU.
#define QT 128
#define SK 64

__global__ __launch_bounds__(512) void flash5(const u16* __restrict__ q16,
                                              const u16* __restrict__ k16,
                                              const u16* __restrict__ vt16,
                                              u16* __restrict__ y16, int T) {
    __shared__ u16 Ks[2][SK * 128];
    __shared__ u16 Vt[2][HD * 64];

    const int tid = threadIdx.x;
    const int wave = tid >> 6;        // 0..7
    const int lane = tid & 63;
    const int l16 = lane & 15;
    const int quad = lane >> 4;

    const int bid = blockIdx.x;
    const int bh = bid & 31;          // b*NH + h
    const int qi = bid >> 5;          // 0..nqt-1
    const int nqt = T / QT;           // 16
    const int qt = (qi < (nqt >> 1)) ? qi : (nqt - 1 - (qi - (nqt >> 1)));
    const int h = bh & 15;
    const int b = bh >> 4;
    const int kv = h / GQ;

    const u16* kg = k16 + ((size_t)b * T * NKV + kv) * HD;
    const u16* vg = vt16 + (size_t)(b * NKV + kv) * HD * T;

    const int krow_in_seg = lane >> 4;          // 0..3
    const int kclog_base = lane & 15;           // phys chunk; logical = phys ^ (r&15)
    const int vrow_in_seg = lane >> 3;          // 0..7
    const int vclog = (lane & 7) ^ (lane >> 3); // logical chunk

    const int q0 = qt * QT;
    const int qglob = q0 + wave * 16 + l16;
    const int nts = q0 / SK + 2;      // two diagonal tiles

    bf16x8 qf[4];
    {
        const u16* qp = q16 + ((size_t)(b * T + qglob) * NH + h) * HD;
#pragma unroll
        for (int kc = 0; kc < 4; kc++)
            qf[kc] = *(const bf16x8*)(qp + kc * 32 + quad * 8);
    }

    f32x4 of[8];
#pragma unroll
    for (int i = 0; i < 8; i++) of[i] = (f32x4){0.f, 0.f, 0.f, 0.f};
    float m_i = -1e30f, l_i = 0.0f;

    // preload tile 0: 16 K segs + 16 V segs, 2+2 per wave
#pragma unroll
    for (int j = 0; j < 2; j++) {
        const int seg = wave * 2 + j;
        const int r = seg * 4 + krow_in_seg;
        const int clog = kclog_base ^ (r & 15);
        ASYNC_LOAD16(kg + (size_t)r * (NKV * HD) + clog * 8, &Ks[0][seg * 512]);
        const int d = seg * 8 + vrow_in_seg;
        ASYNC_LOAD16(vg + (size_t)d * T + vclog * 8, &Vt[0][seg * 512]);
    }

    for (int it = 0; it < nts; it++) {
        const int cur = it & 1;
        __syncthreads();   // drains DMA for tile `it` (one full phase in flight)

        if (it + 1 < nts) {
            const int s1 = (it + 1) * SK;
#pragma unroll
            for (int j = 0; j < 2; j++) {
                const int seg = wave * 2 + j;
                const int r = seg * 4 + krow_in_seg;
                const int clog = kclog_base ^ (r & 15);
                ASYNC_LOAD16(kg + (size_t)(s1 + r) * (NKV * HD) + clog * 8,
                             &Ks[cur ^ 1][seg * 512]);
                const int d = seg * 8 + vrow_in_seg;
                ASYNC_LOAD16(vg + (size_t)d * T + s1 + vclog * 8,
                             &Vt[cur ^ 1][seg * 512]);
            }
        }

        // waves 0-3 are fully masked on the last diagonal tile: skip compute
        if (it == nts - 1 && wave < 4) continue;

        // S^T = K Q^T
        f32x4 sf[4];
#pragma unroll
        for (int st = 0; st < 4; st++) sf[st] = (f32x4){0.f, 0.f, 0.f, 0.f};
#pragma unroll
        for (int kc = 0; kc < 4; kc++)
#pragma unroll
            for (int st = 0; st < 4; st++) {
                const int row = st * 16 + l16;
                bf16x8 kf = *(const bf16x8*)
                    &Ks[cur][row * 128 + (((kc * 4 + quad) ^ l16) * 8)];
                sf[st] = __builtin_amdgcn_mfma_f32_16x16x32_bf16(kf, qf[kc], sf[st], 0, 0, 0);
            }

        if (it >= nts - 2) {  // diagonal tiles: causal mask
            const int s0 = it * SK;
#pragma unroll
            for (int st = 0; st < 4; st++)
#pragma unroll
                for (int r = 0; r < 4; r++)
                    if (s0 + st * 16 + quad * 4 + r > qglob) sf[st][r] = -1e30f;
        }

        float tm = -1e30f;
#pragma unroll
        for (int st = 0; st < 4; st++)
#pragma unroll
            for (int r = 0; r < 4; r++) tm = fmaxf(tm, sf[st][r]);
        tm = fmaxf(tm, __shfl_xor(tm, 16));
        tm = fmaxf(tm, __shfl_xor(tm, 32));

        // defer-max (T13): only rescale when max grew by > 8 (log2 units)
        if (__ballot(tm > m_i + 8.0f)) {
            const float mnew = fmaxf(m_i, tm);
            const float alpha = fast_exp2(m_i - mnew);
            m_i = mnew;
            l_i *= alpha;
#pragma unroll
            for (int dt = 0; dt < 8; dt++)
#pragma unroll
                for (int r = 0; r < 4; r++) of[dt][r] *= alpha;
        }

        f16x4 pf[4];
        float ls = 0.0f;
#pragma unroll
        for (int st = 0; st < 4; st++)
#pragma unroll
            for (int r = 0; r < 4; r++) {
                float e = fast_exp2(sf[st][r] - m_i);
                ls += e;
                pf[st][r] = (_Float16)e;
            }
        ls += __shfl_xor(ls, 16);
        ls += __shfl_xor(ls, 32);
        l_i += ls;

        // O^T += V^T P^T
#pragma unroll
        for (int st = 0; st < 4; st++) {
            const int clog = st * 2 + (quad >> 1);
#pragma unroll
            for (int dt = 0; dt < 8; dt++) {
                const int d = dt * 16 + l16;
                const int phys = clog ^ (l16 & 7);
                f16x4 va = *(const f16x4*)
                    &Vt[cur][d * 64 + phys * 8 + (quad & 1) * 4];
                of[dt] = __builtin_amdgcn_mfma_f32_16x16x16f16(va, pf[st], of[dt], 0, 0, 0);
            }
        }
    }

    const float inv = 1.0f / l_i;
    u16* yp = y16 + ((size_t)(b * T + qglob) * NH + h) * HD + quad * 4;
#pragma unroll
    for (int dt = 0; dt < 8; dt++) {
        ushort4 o;
        o.x = (u16)f2bf(of[dt][0] * inv);
        o.y = (u16)f2bf(of[dt][1] * inv);
        o.z = (u16)f2bf(of[dt][2] * inv);
        o.w = (u16)f2bf(of[dt][3] * inv);
        *(ushort4*)(yp + dt * 16) = o;
    }
}

// ---------------------------------------------------------------------------
extern "C" void kernel_launch(void* const* d_in, const int* in_sizes, int n_in,
                              void* d_out, int out_size, void* d_ws, size_t ws_size,
                              hipStream_t stream) {
    const float* x      = (const float*)d_in[0];
    const float* Wq     = (const float*)d_in[1];
    const float* Wk     = (const float*)d_in[2];
    const float* Wv     = (const float*)d_in[3];
    const float* Wp     = (const float*)d_in[4];
    const float* q_gain = (const float*)d_in[5];
    float* out = (float*)d_out;

    const int B = 2;
    const int BT = in_sizes[0] / DIM;      // 4096
    const int T = BT / B;                  // 2048
    const int KD = NKV * HD;               // 512

    u16* x16   = (u16*)d_ws;                        // BT*DIM        (later y16)
    u16* wqkv  = x16 + (size_t)BT * DIM;            // 3072*DIM
    u16* wp16  = wqkv + (size_t)3072 * DIM;         // DIM*DIM
    u16* q16   = wp16 + (size_t)DIM * DIM;          // BT*DIM
    u16* k16   = q16 + (size_t)BT * DIM;            // BT*KD
    u16* vt16  = k16 + (size_t)BT * KD;             // BT*KD
    float* ctab = (float*)(vt16 + (size_t)BT * KD); // T*64
    float* stab = ctab + (size_t)T * 64;            // T*64
    u16* y16   = x16;

    double base = 10000.0;
    if (T > 1024) base = 10000.0 * pow((double)T / 1024.0, 128.0 / 126.0);
    const float l2b64 = (float)(log2(base) / 64.0);

    const int nx4  = BT * DIM / 4;
    const int total4 = nx4 + 2 * (DIM * DIM / 4) + 2 * (KD * DIM / 4);
    const int nblk_cvt = (total4 + 255) / 256;
    const int nblk_rope = (T * 64 + 255) / 256;

    cvt_fused<<<nblk_cvt + nblk_rope, 256, 0, stream>>>(
        x, Wq, Wk, Wv, Wp, x16, wqkv, wp16, ctab, stab, l2b64, nx4, total4, nblk_cvt);

    gemm256<1, 4><<<dim3(BT / 256, 3072 / BN), 512, 0, stream>>>(
        x16, wqkv, nullptr, 0, q16, k16, vt16, ctab, stab, q_gain, T);

    flash5<<<32 * (T / QT), 512, 0, stream>>>(q16, k16, vt16, y16, T);

    gemm256<0, 2><<<dim3(BT / 128, DIM / BN), 512, 0, stream>>>(
        y16, wp16, out, DIM, nullptr, nullptr, nullptr, nullptr, nullptr, nullptr, T);
}